// Round 11
// baseline (680.761 us; speedup 1.0000x reference)
//
#include <hip/hip_runtime.h>
#include <hip/hip_bf16.h>

#define HW 9216
#define CDIM 128
#define ROWS_W 64                   // rows per wave (4 x 16-row m-frags)
#define NCH 12                      // 16-col chains per wave
#define COLS_W (NCH * 16)           // 192
#define GRID_I (HW / (ROWS_W * 4))  // 36
#define GRID_J (HW / COLS_W)        // 48
#define GRID_T (GRID_I * GRID_J)    // 1728
#define NPART (GRID_T * 4)          // 6912 per-wave partial pairs

using bf16 = __hip_bfloat16;
typedef __attribute__((ext_vector_type(4))) float f32x4;
typedef __attribute__((ext_vector_type(8))) short s16x8;

#define EXP_SCALE 36.067376022224085f

#if __has_builtin(__builtin_amdgcn_exp2f)
#define FEXP2(x) __builtin_amdgcn_exp2f(x)
#else
#define FEXP2(x) exp2f(x)
#endif

// ---------------------------------------------------------------------------
// Kernel 1: x[b] [C][HW] f32 -> frag[b] in 16x16x32 MFMA fragment layout
// (identical to R10).
// ---------------------------------------------------------------------------
__global__ __launch_bounds__(256) void prep_kernel(const float* __restrict__ x,
                                                   bf16* __restrict__ frag) {
    __shared__ float tile[64][65];
    const float* xs = x + (size_t)blockIdx.z * CDIM * HW;
    bf16* fs = frag + (size_t)blockIdx.z * HW * CDIM;
    float scale = (blockIdx.z == 0) ? EXP_SCALE : 1.0f;

    int p0 = blockIdx.x * 64;
    int c0 = blockIdx.y * 64;
    int t  = threadIdx.x;

    int pc = t & 63;
    int cr = t >> 6;
#pragma unroll
    for (int i = 0; i < 16; ++i) {
        int clc = cr + i * 4;
        tile[clc][pc] = xs[(size_t)(c0 + clc) * HW + p0 + pc];
    }
    __syncthreads();

#pragma unroll
    for (int q = 0; q < 2; ++q) {
        int ch   = q * 256 + t;
        int row  = ch & 15;
        int kgq  = (ch >> 4) & 3;
        int ksl  = (ch >> 6) & 1;
        int ib   = (ch >> 7) & 3;
        s16x8 v;
#pragma unroll
        for (int e = 0; e < 8; ++e) {
            __hip_bfloat16 h = __float2bfloat16(tile[ksl * 32 + kgq * 8 + e][ib * 16 + row] * scale);
            v[e] = *reinterpret_cast<short*>(&h);
        }
        size_t chunk = ((size_t)(p0 / 16 + ib) * 4 + (c0 / 32 + ksl)) * 64 + kgq * 16 + row;
        *(s16x8*)(&fs[chunk * 8]) = v;
    }
}

// ---------------------------------------------------------------------------
// Kernel 2 body, ablation-templated. MODE: 0=full epilogue (exp+mask+sums),
// 1=plain sums only (no exp/mask), 2=no epilogue (acc kept live via asm).
// REP repeats the whole chain sweep (accumulating; MODE0 divides by REP ->
// numerics ~identical). Rolling prefetch wraps to chain 0 across reps.
// ---------------------------------------------------------------------------
template<int MODE, int REP>
__device__ __forceinline__ void simsum_body(const bf16* __restrict__ frag1,
                                            const bf16* __restrict__ frag2,
                                            const int* __restrict__ label,
                                            float* __restrict__ partials) {
    int t    = threadIdx.x;
    int w    = t >> 6;
    int lane = t & 63;
    int lr   = lane & 15;
    int kg   = lane >> 4;

    int orig = blockIdx.x;
    int wg   = (orig & 7) * (GRID_T / 8) + (orig >> 3);
    int jw   = wg / GRID_I;
    int iw   = wg % GRID_I;

    int r0 = iw * (ROWS_W * 4) + w * ROWS_W;
    int c0 = jw * COLS_W;
    int jb0 = c0 / 16;

    const s16x8* F1 = ((const s16x8*)frag1) + lane;
    const s16x8* F2 = ((const s16x8*)frag2) + lane;

    s16x8 af[4][4];
#pragma unroll
    for (int m = 0; m < 4; ++m)
#pragma unroll
        for (int ks = 0; ks < 4; ++ks)
            af[m][ks] = F1[(size_t)((r0 / 16 + m) * 4 + ks) * 64];

    unsigned pk = 0;
    if constexpr (MODE == 0) {
#pragma unroll
        for (int m = 0; m < 4; ++m) {
            int4 v = *(const int4*)(&label[r0 + m * 16 + kg * 4]);
            unsigned b = (unsigned)v.x | ((unsigned)v.y << 2) |
                         ((unsigned)v.z << 4) | ((unsigned)v.w << 6);
            pk |= b << (8 * m);
        }
    }

    const int* lab2 = label + HW;
    float tot = 0.f, pos = 0.f;

    s16x8 bf[4];
#pragma unroll
    for (int ks = 0; ks < 4; ++ks)
        bf[ks] = F2[(size_t)(jb0 * 4 + ks) * 64];

#pragma unroll 1
    for (int rep = 0; rep < REP; ++rep) {
#pragma unroll
        for (int ch = 0; ch < NCH; ++ch) {
            int nb = (ch + 1 < NCH) ? (ch + 1) : 0;   // wraps: feeds next rep too
            const s16x8* bnext = F2 + (size_t)((jb0 + nb) * 4) * 64;

            unsigned z = 0;
            if constexpr (MODE == 0) {
                int g2 = lab2[c0 + ch * 16 + lr];
                unsigned d = pk ^ ((unsigned)g2 * 0x55555555u);
                z = ~(d | (d >> 1)) & 0x55555555u;
            }

            f32x4 acc[4] = {};
#pragma unroll
            for (int ks = 0; ks < 4; ++ks) {
                s16x8 b = bf[ks];
#pragma unroll
                for (int m = 0; m < 4; ++m)
                    acc[m] = __builtin_amdgcn_mfma_f32_16x16x32_bf16(af[m][ks], b, acc[m], 0, 0, 0);
                bf[ks] = bnext[(size_t)ks * 64];
            }

            if constexpr (MODE == 0) {
#pragma unroll
                for (int m = 0; m < 4; ++m)
#pragma unroll
                    for (int r = 0; r < 4; ++r) {
                        float e = FEXP2(acc[m][r]);
                        tot += e;
                        pos += ((z >> (2 * (m * 4 + r))) & 1u) ? e : 0.f;
                    }
            } else if constexpr (MODE == 1) {
#pragma unroll
                for (int m = 0; m < 4; ++m)
#pragma unroll
                    for (int r = 0; r < 4; ++r)
                        tot += acc[m][r];
            } else {
                // keep MFMAs + feeding loads live without epilogue cost
                asm volatile("" :: "v"(acc[0][0]), "v"(acc[1][0]),
                                   "v"(acc[2][0]), "v"(acc[3][0]));
            }
        }
    }

    if constexpr (MODE == 0) { tot *= (1.0f / REP); pos *= (1.0f / REP); }

#pragma unroll
    for (int off = 32; off; off >>= 1) {
        tot += __shfl_down(tot, off);
        pos += __shfl_down(pos, off);
    }
    if (lane == 0) {
        int wid = orig * 4 + w;
        partials[wid * 2]     = tot;
        partials[wid * 2 + 1] = pos;
    }
}

__global__ __launch_bounds__(256, 4) void simsum_full(const bf16* __restrict__ f1,
                                                      const bf16* __restrict__ f2,
                                                      const int* __restrict__ lab,
                                                      float* __restrict__ p) {
    simsum_body<0, 2>(f1, f2, lab, p);
}
__global__ __launch_bounds__(256, 4) void simsum_nosm(const bf16* __restrict__ f1,
                                                      const bf16* __restrict__ f2,
                                                      const int* __restrict__ lab,
                                                      float* __restrict__ p) {
    simsum_body<1, 6>(f1, f2, lab, p + 2 * (size_t)NPART);
}
__global__ __launch_bounds__(256, 4) void simsum_noepi(const bf16* __restrict__ f1,
                                                       const bf16* __restrict__ f2,
                                                       const int* __restrict__ lab,
                                                       float* __restrict__ p) {
    simsum_body<2, 10>(f1, f2, lab, p + 4 * (size_t)NPART);
}

// ---------------------------------------------------------------------------
// Kernel 3: reduce partial pairs (full variant only), loss = -log(pos/tot)/hw^2
// ---------------------------------------------------------------------------
__global__ __launch_bounds__(256) void finalize_kernel(const float* __restrict__ partials,
                                                       float* __restrict__ out) {
    double tot = 0.0, pos = 0.0;
    int t = threadIdx.x;
    for (int i = t; i < NPART; i += 256) {
        tot += (double)partials[i * 2];
        pos += (double)partials[i * 2 + 1];
    }
#pragma unroll
    for (int off = 32; off; off >>= 1) {
        tot += __shfl_down(tot, off);
        pos += __shfl_down(pos, off);
    }
    __shared__ double rt[4], rp[4];
    int w = t >> 6, lane = t & 63;
    if (lane == 0) { rt[w] = tot; rp[w] = pos; }
    __syncthreads();
    if (t == 0) {
        double T = rt[0] + rt[1] + rt[2] + rt[3];
        double P = rp[0] + rp[1] + rp[2] + rp[3];
        double hw2 = (double)HW * (double)HW;
        out[0] = (float)(-log(P / T) / hw2);
    }
}

extern "C" void kernel_launch(void* const* d_in, const int* in_sizes, int n_in,
                              void* d_out, int out_size, void* d_ws, size_t ws_size,
                              hipStream_t stream) {
    const float* x     = (const float*)d_in[0];
    const int*   label = (const int*)d_in[1];
    float*       out   = (float*)d_out;

    bf16*  frag  = (bf16*)d_ws;
    float* parts = (float*)((char*)d_ws + 2 * (size_t)HW * CDIM * sizeof(bf16));
    bf16*  frag2 = frag + (size_t)HW * CDIM;

    dim3 g1(HW / 64, CDIM / 64, 2);
    prep_kernel<<<g1, 256, 0, stream>>>(x, frag);

    simsum_full <<<GRID_T, 256, 0, stream>>>(frag, frag2, label, parts);
    simsum_nosm <<<GRID_T, 256, 0, stream>>>(frag, frag2, label, parts);
    simsum_noepi<<<GRID_T, 256, 0, stream>>>(frag, frag2, label, parts);

    finalize_kernel<<<1, 256, 0, stream>>>(parts, out);
}

// Round 12
// 187.852 us; speedup vs baseline: 3.6239x; 3.6239x over previous
//
#include <hip/hip_runtime.h>
#include <hip/hip_bf16.h>

#define HW 9216
#define CDIM 128
#define ROWS_W 64                   // rows per wave (4 x 16-row m-frags)
#define NCH 12                      // 16-col chains per wave
#define COLS_W (NCH * 16)           // 192
#define GRID_I (HW / (ROWS_W * 4))  // 36
#define GRID_J (HW / COLS_W)        // 48
#define GRID_T (GRID_I * GRID_J)    // 1728
#define NPART (GRID_T * 4)          // per-wave partial pairs

using bf16 = __hip_bfloat16;
typedef __attribute__((ext_vector_type(4))) float f32x4;
typedef __attribute__((ext_vector_type(8))) short s16x8;

#define EXP_SCALE 36.067376022224085f

#if __has_builtin(__builtin_amdgcn_exp2f)
#define FEXP2(x) __builtin_amdgcn_exp2f(x)
#else
#define FEXP2(x) exp2f(x)
#endif

// ---------------------------------------------------------------------------
// Kernel 1: x[b] [C][HW] f32 -> frag[b] in 16x16x32 MFMA fragment layout
// (identical to R10): chunk[(ib16*4+ks)*64 + kg*16 + row] = 8 bf16.
// ---------------------------------------------------------------------------
__global__ __launch_bounds__(256) void prep_kernel(const float* __restrict__ x,
                                                   bf16* __restrict__ frag) {
    __shared__ float tile[64][65];
    const float* xs = x + (size_t)blockIdx.z * CDIM * HW;
    bf16* fs = frag + (size_t)blockIdx.z * HW * CDIM;
    float scale = (blockIdx.z == 0) ? EXP_SCALE : 1.0f;

    int p0 = blockIdx.x * 64;
    int c0 = blockIdx.y * 64;
    int t  = threadIdx.x;

    int pc = t & 63;
    int cr = t >> 6;
#pragma unroll
    for (int i = 0; i < 16; ++i) {
        int clc = cr + i * 4;
        tile[clc][pc] = xs[(size_t)(c0 + clc) * HW + p0 + pc];
    }
    __syncthreads();

#pragma unroll
    for (int q = 0; q < 2; ++q) {
        int ch   = q * 256 + t;
        int row  = ch & 15;
        int kgq  = (ch >> 4) & 3;
        int ksl  = (ch >> 6) & 1;
        int ib   = (ch >> 7) & 3;
        s16x8 v;
#pragma unroll
        for (int e = 0; e < 8; ++e) {
            __hip_bfloat16 h = __float2bfloat16(tile[ksl * 32 + kgq * 8 + e][ib * 16 + row] * scale);
            v[e] = *reinterpret_cast<short*>(&h);
        }
        size_t chunk = ((size_t)(p0 / 16 + ib) * 4 + (c0 / 32 + ksl)) * 64 + kgq * 16 + row;
        *(s16x8*)(&fs[chunk * 8]) = v;
    }
}

// ---------------------------------------------------------------------------
// Kernel 2: barrier-free, LDS-free, fragment-layout loads. NEW vs R10:
// depth-2 register double-buffer (bP/bQ), deferred epilogue (prev chain's
// exp overlaps current chain's MFMA execute window), setprio around MFMA,
// split sum accumulators. grid = 1728, block = 256, 3 waves/SIMD.
// ---------------------------------------------------------------------------
__global__ __launch_bounds__(256, 3) void simsum_kernel(const bf16* __restrict__ frag1,
                                                        const bf16* __restrict__ frag2,
                                                        const int* __restrict__ label,
                                                        float* __restrict__ partials) {
    int t    = threadIdx.x;
    int w    = t >> 6;
    int lane = t & 63;
    int lr   = lane & 15;
    int kg   = lane >> 4;

    int orig = blockIdx.x;
    int wg   = (orig & 7) * (GRID_T / 8) + (orig >> 3);
    int jw   = wg / GRID_I;
    int iw   = wg % GRID_I;

    int r0 = iw * (ROWS_W * 4) + w * ROWS_W;
    int c0 = jw * COLS_W;
    int jb0 = c0 / 16;

    const s16x8* F1 = ((const s16x8*)frag1) + lane;
    const s16x8* F2 = ((const s16x8*)frag2) + lane;

    // A fragments: one coalesced 1KB load each
    s16x8 af[4][4];
#pragma unroll
    for (int m = 0; m < 4; ++m)
#pragma unroll
        for (int ks = 0; ks < 4; ++ks)
            af[m][ks] = F1[(size_t)((r0 / 16 + m) * 4 + ks) * 64];

    // 2-bit packed row labels: bit 2*(m*4+r) pair = label of row r0+m*16+kg*4+r
    unsigned pk = 0;
#pragma unroll
    for (int m = 0; m < 4; ++m) {
        int4 v = *(const int4*)(&label[r0 + m * 16 + kg * 4]);
        unsigned b = (unsigned)v.x | ((unsigned)v.y << 2) |
                     ((unsigned)v.z << 4) | ((unsigned)v.w << 6);
        pk |= b << (8 * m);
    }

    const int* lab2 = label + HW;
    float tsum[4] = {0.f, 0.f, 0.f, 0.f};
    float psum[4] = {0.f, 0.f, 0.f, 0.f};

    // depth-2 double buffer
    s16x8 bP[4], bQ[4];
#pragma unroll
    for (int ks = 0; ks < 4; ++ks) {
        bP[ks] = F2[(size_t)((jb0 + 0) * 4 + ks) * 64];
        bQ[ks] = F2[(size_t)((jb0 + 1) * 4 + ks) * 64];
    }

    // per-chain mask (uses compile-time ch after unroll)
    auto zcalc = [&](int ch) -> unsigned {
        int g2 = lab2[c0 + ch * 16 + lr];
        unsigned d = pk ^ ((unsigned)g2 * 0x55555555u);
        return ~(d | (d >> 1)) & 0x55555555u;
    };

    // MFMA cluster for chain ch from BUF; reload BUF <- chain ch+2 (wrapped)
    auto cluster = [&](int ch, f32x4 (&acc)[4], s16x8 (&buf)[4]) {
        int nb = (ch + 2 < NCH) ? ch + 2 : ch + 2 - NCH;
        const s16x8* bnext = F2 + (size_t)((jb0 + nb) * 4) * 64;
#pragma unroll
        for (int m = 0; m < 4; ++m) acc[m] = f32x4{0.f, 0.f, 0.f, 0.f};
        __builtin_amdgcn_s_setprio(1);
#pragma unroll
        for (int ks = 0; ks < 4; ++ks) {
            s16x8 b = buf[ks];
            acc[0] = __builtin_amdgcn_mfma_f32_16x16x32_bf16(af[0][ks], b, acc[0], 0, 0, 0);
            acc[1] = __builtin_amdgcn_mfma_f32_16x16x32_bf16(af[1][ks], b, acc[1], 0, 0, 0);
            acc[2] = __builtin_amdgcn_mfma_f32_16x16x32_bf16(af[2][ks], b, acc[2], 0, 0, 0);
            acc[3] = __builtin_amdgcn_mfma_f32_16x16x32_bf16(af[3][ks], b, acc[3], 0, 0, 0);
            buf[ks] = bnext[(size_t)ks * 64];        // depth-2 reload
        }
        __builtin_amdgcn_s_setprio(0);
    };

    // deferred epilogue: exp + masked/total accumulate of a FINISHED chain
    auto epi = [&](const f32x4 (&acc)[4], unsigned z) {
#pragma unroll
        for (int m = 0; m < 4; ++m) {
#pragma unroll
            for (int r = 0; r < 4; ++r) {
                float e = FEXP2(acc[m][r]);
                tsum[m] += e;
                psum[m] += ((z >> (2 * (m * 4 + r))) & 1u) ? e : 0.f;
            }
        }
    };

    f32x4 accA[4], accB[4];
    unsigned zA, zB;

    zA = zcalc(0);
    cluster(0, accA, bP);
#pragma unroll
    for (int c = 1; c <= NCH - 3; c += 2) {          // chains 1..10 in pairs
        zB = zcalc(c);
        cluster(c, accB, bQ);
        epi(accA, zA);                               // overlaps accB's MFMAs
        zA = zcalc(c + 1);
        cluster(c + 1, accA, bP);
        epi(accB, zB);                               // overlaps accA's MFMAs
    }
    zB = zcalc(NCH - 1);
    cluster(NCH - 1, accB, bQ);
    epi(accA, zA);
    epi(accB, zB);

    float tot = (tsum[0] + tsum[1]) + (tsum[2] + tsum[3]);
    float pos = (psum[0] + psum[1]) + (psum[2] + psum[3]);

#pragma unroll
    for (int off = 32; off; off >>= 1) {
        tot += __shfl_down(tot, off);
        pos += __shfl_down(pos, off);
    }
    if (lane == 0) {
        int wid = orig * 4 + w;
        partials[wid * 2]     = tot;
        partials[wid * 2 + 1] = pos;
    }
}

// ---------------------------------------------------------------------------
// Kernel 3: reduce partial pairs, loss = -log(pos/tot)/hw^2
// ---------------------------------------------------------------------------
__global__ __launch_bounds__(256) void finalize_kernel(const float* __restrict__ partials,
                                                       float* __restrict__ out) {
    double tot = 0.0, pos = 0.0;
    int t = threadIdx.x;
    for (int i = t; i < NPART; i += 256) {
        tot += (double)partials[i * 2];
        pos += (double)partials[i * 2 + 1];
    }
#pragma unroll
    for (int off = 32; off; off >>= 1) {
        tot += __shfl_down(tot, off);
        pos += __shfl_down(pos, off);
    }
    __shared__ double rt[4], rp[4];
    int w = t >> 6, lane = t & 63;
    if (lane == 0) { rt[w] = tot; rp[w] = pos; }
    __syncthreads();
    if (t == 0) {
        double T = rt[0] + rt[1] + rt[2] + rt[3];
        double P = rp[0] + rp[1] + rp[2] + rp[3];
        double hw2 = (double)HW * (double)HW;
        out[0] = (float)(-log(P / T) / hw2);
    }
}

extern "C" void kernel_launch(void* const* d_in, const int* in_sizes, int n_in,
                              void* d_out, int out_size, void* d_ws, size_t ws_size,
                              hipStream_t stream) {
    const float* x     = (const float*)d_in[0];   // (4,128,96,96) f32; only b=0,1 used
    const int*   label = (const int*)d_in[1];     // (4,1,96,96) i32; only b=0,1 used
    float*       out   = (float*)d_out;

    bf16*  frag  = (bf16*)d_ws;                       // frag1 (pre-scaled), frag2
    float* parts = (float*)((char*)d_ws + 2 * (size_t)HW * CDIM * sizeof(bf16));

    dim3 g1(HW / 64, CDIM / 64, 2);
    prep_kernel<<<g1, 256, 0, stream>>>(x, frag);

    simsum_kernel<<<GRID_T, 256, 0, stream>>>(frag, frag + (size_t)HW * CDIM, label, parts);

    finalize_kernel<<<1, 256, 0, stream>>>(parts, out);
}

// Round 13
// 47.511 us; speedup vs baseline: 14.3285x; 3.9539x over previous
//
#include <hip/hip_runtime.h>
#include <hip/hip_bf16.h>

#define HW 9216
#define CDIM 128
#define ROWS_W 128                  // rows per wave (8 x 16-row m-frags)
#define NCH 12                      // 16-col chains per wave
#define COLS_W (NCH * 16)           // 192
#define WPB 4                       // waves per block (512 rows/block)
#define GRID_I (HW / (ROWS_W * WPB))// 18
#define GRID_J (HW / COLS_W)        // 48
#define GRID_T (GRID_I * GRID_J)    // 864 (mult of 8 -> bijective swizzle)
#define NPART (GRID_T * WPB)        // 3456 per-wave partial pairs

using bf16 = __hip_bfloat16;
typedef __attribute__((ext_vector_type(4))) float f32x4;
typedef __attribute__((ext_vector_type(8))) short s16x8;

#define EXP_SCALE 36.067376022224085f

#if __has_builtin(__builtin_amdgcn_exp2f)
#define FEXP2(x) __builtin_amdgcn_exp2f(x)
#else
#define FEXP2(x) exp2f(x)
#endif

// ---------------------------------------------------------------------------
// Kernel 1: x[b] [C][HW] f32 -> frag[b] in 16x16x32 MFMA fragment layout
// (identical to R10): chunk[(ib16*4+ks)*64 + kg*16 + row] = 8 bf16.
// ---------------------------------------------------------------------------
__global__ __launch_bounds__(256) void prep_kernel(const float* __restrict__ x,
                                                   bf16* __restrict__ frag) {
    __shared__ float tile[64][65];
    const float* xs = x + (size_t)blockIdx.z * CDIM * HW;
    bf16* fs = frag + (size_t)blockIdx.z * HW * CDIM;
    float scale = (blockIdx.z == 0) ? EXP_SCALE : 1.0f;

    int p0 = blockIdx.x * 64;
    int c0 = blockIdx.y * 64;
    int t  = threadIdx.x;

    int pc = t & 63;
    int cr = t >> 6;
#pragma unroll
    for (int i = 0; i < 16; ++i) {
        int clc = cr + i * 4;
        tile[clc][pc] = xs[(size_t)(c0 + clc) * HW + p0 + pc];
    }
    __syncthreads();

#pragma unroll
    for (int q = 0; q < 2; ++q) {
        int ch   = q * 256 + t;
        int row  = ch & 15;
        int kgq  = (ch >> 4) & 3;
        int ksl  = (ch >> 6) & 1;
        int ib   = (ch >> 7) & 3;
        s16x8 v;
#pragma unroll
        for (int e = 0; e < 8; ++e) {
            __hip_bfloat16 h = __float2bfloat16(tile[ksl * 32 + kgq * 8 + e][ib * 16 + row] * scale);
            v[e] = *reinterpret_cast<short*>(&h);
        }
        size_t chunk = ((size_t)(p0 / 16 + ib) * 4 + (c0 / 32 + ksl)) * 64 + kgq * 16 + row;
        *(s16x8*)(&fs[chunk * 8]) = v;
    }
}

// ---------------------------------------------------------------------------
// Kernel 2: barrier-free, LDS-free, fragment-layout loads. Wave = 128 rows x
// 192 cols (8 m-frags): halves register-fill traffic vs 64-row waves and
// doubles MFMA per B-load. Depth-2 ping-pong B prefetch; bit-mask epilogue;
// vector f32x4 sums (v_pk_add). ~217 VGPR -> launch_bounds(256,2), no spill.
// grid = 864 (XCD-swizzled), block = 256.
// ---------------------------------------------------------------------------
__global__ __launch_bounds__(256, 2) void simsum_kernel(const bf16* __restrict__ frag1,
                                                        const bf16* __restrict__ frag2,
                                                        const int* __restrict__ label,
                                                        float* __restrict__ partials) {
    int t    = threadIdx.x;
    int w    = t >> 6;
    int lane = t & 63;
    int lr   = lane & 15;
    int kg   = lane >> 4;

    int orig = blockIdx.x;
    int wg   = (orig & 7) * (GRID_T / 8) + (orig >> 3);
    int jw   = wg / GRID_I;
    int iw   = wg % GRID_I;

    int r0 = iw * (ROWS_W * WPB) + w * ROWS_W;   // this wave's 128 rows
    int c0 = jw * COLS_W;
    int jb0 = c0 / 16;

    const s16x8* F1 = ((const s16x8*)frag1) + lane;
    const s16x8* F2 = ((const s16x8*)frag2) + lane;

    // A fragments: af[m][ks], 8 m-frags x 4 ks, one coalesced 1KB load each
    s16x8 af[8][4];
#pragma unroll
    for (int m = 0; m < 8; ++m)
#pragma unroll
        for (int ks = 0; ks < 4; ++ks)
            af[m][ks] = F1[(size_t)((r0 / 16 + m) * 4 + ks) * 64];

    // 2-bit packed row labels, 32 rows of C per lane:
    // row(m,r) = r0 + m*16 + kg*4 + r ; pkA covers m=0..3, pkB m=4..7
    unsigned pkA = 0, pkB = 0;
#pragma unroll
    for (int m = 0; m < 4; ++m) {
        int4 va = *(const int4*)(&label[r0 + m * 16 + kg * 4]);
        pkA |= ((unsigned)va.x | ((unsigned)va.y << 2) |
                ((unsigned)va.z << 4) | ((unsigned)va.w << 6)) << (8 * m);
        int4 vb = *(const int4*)(&label[r0 + (m + 4) * 16 + kg * 4]);
        pkB |= ((unsigned)vb.x | ((unsigned)vb.y << 2) |
                ((unsigned)vb.z << 4) | ((unsigned)vb.w << 6)) << (8 * m);
    }

    const int* lab2 = label + HW;
    f32x4 tsum = {0.f, 0.f, 0.f, 0.f};
    f32x4 psum = {0.f, 0.f, 0.f, 0.f};

    // depth-2 ping-pong prefetch buffers
    s16x8 bP[4], bQ[4];
#pragma unroll
    for (int ks = 0; ks < 4; ++ks) {
        bP[ks] = F2[(size_t)((jb0 + 0) * 4 + ks) * 64];
        bQ[ks] = F2[(size_t)((jb0 + 1) * 4 + ks) * 64];
    }

    // one chain: 32 MFMA from buf (reloading buf <- chain ch+2), then epilogue
    auto chain = [&](int ch, s16x8 (&buf)[4]) {
        int g2 = lab2[c0 + ch * 16 + lr];
        unsigned g2r = (unsigned)g2 * 0x55555555u;
        unsigned dA = pkA ^ g2r, dB = pkB ^ g2r;
        unsigned zA = ~(dA | (dA >> 1)) & 0x55555555u;
        unsigned zB = ~(dB | (dB >> 1)) & 0x55555555u;

        int nb = (ch + 2 < NCH) ? ch + 2 : ch + 2 - NCH;
        const s16x8* bnext = F2 + (size_t)((jb0 + nb) * 4) * 64;

        f32x4 acc[8] = {};
        __builtin_amdgcn_s_setprio(1);
#pragma unroll
        for (int ks = 0; ks < 4; ++ks) {
            s16x8 b = buf[ks];
#pragma unroll
            for (int m = 0; m < 8; ++m)
                acc[m] = __builtin_amdgcn_mfma_f32_16x16x32_bf16(af[m][ks], b, acc[m], 0, 0, 0);
            buf[ks] = bnext[(size_t)ks * 64];        // depth-2 reload
        }
        __builtin_amdgcn_s_setprio(0);

        // epilogue: exp + masked/total accumulate (f32x4 lanes -> v_pk_add)
#pragma unroll
        for (int m = 0; m < 8; ++m) {
            unsigned z = (m < 4) ? zA : zB;
            int mb = m & 3;
            f32x4 ev;
#pragma unroll
            for (int r = 0; r < 4; ++r)
                ev[r] = FEXP2(acc[m][r]);
            tsum += ev;
            f32x4 pv;
#pragma unroll
            for (int r = 0; r < 4; ++r)
                pv[r] = ((z >> (2 * (mb * 4 + r))) & 1u) ? ev[r] : 0.f;
            psum += pv;
        }
    };

#pragma unroll
    for (int c = 0; c < NCH; c += 2) {
        chain(c,     bP);
        chain(c + 1, bQ);
    }

    float tot = (tsum[0] + tsum[1]) + (tsum[2] + tsum[3]);
    float pos = (psum[0] + psum[1]) + (psum[2] + psum[3]);

#pragma unroll
    for (int off = 32; off; off >>= 1) {
        tot += __shfl_down(tot, off);
        pos += __shfl_down(pos, off);
    }
    if (lane == 0) {
        int wid = orig * WPB + w;
        partials[wid * 2]     = tot;
        partials[wid * 2 + 1] = pos;
    }
}

// ---------------------------------------------------------------------------
// Kernel 3: reduce partial pairs, loss = -log(pos/tot)/hw^2
// ---------------------------------------------------------------------------
__global__ __launch_bounds__(256) void finalize_kernel(const float* __restrict__ partials,
                                                       float* __restrict__ out) {
    double tot = 0.0, pos = 0.0;
    int t = threadIdx.x;
    for (int i = t; i < NPART; i += 256) {
        tot += (double)partials[i * 2];
        pos += (double)partials[i * 2 + 1];
    }
#pragma unroll
    for (int off = 32; off; off >>= 1) {
        tot += __shfl_down(tot, off);
        pos += __shfl_down(pos, off);
    }
    __shared__ double rt[4], rp[4];
    int w = t >> 6, lane = t & 63;
    if (lane == 0) { rt[w] = tot; rp[w] = pos; }
    __syncthreads();
    if (t == 0) {
        double T = rt[0] + rt[1] + rt[2] + rt[3];
        double P = rp[0] + rp[1] + rp[2] + rp[3];
        double hw2 = (double)HW * (double)HW;
        out[0] = (float)(-log(P / T) / hw2);
    }
}

extern "C" void kernel_launch(void* const* d_in, const int* in_sizes, int n_in,
                              void* d_out, int out_size, void* d_ws, size_t ws_size,
                              hipStream_t stream) {
    const float* x     = (const float*)d_in[0];   // (4,128,96,96) f32; only b=0,1 used
    const int*   label = (const int*)d_in[1];     // (4,1,96,96) i32; only b=0,1 used
    float*       out   = (float*)d_out;

    bf16*  frag  = (bf16*)d_ws;                       // frag1 (pre-scaled), frag2
    float* parts = (float*)((char*)d_ws + 2 * (size_t)HW * CDIM * sizeof(bf16));

    dim3 g1(HW / 64, CDIM / 64, 2);
    prep_kernel<<<g1, 256, 0, stream>>>(x, frag);

    simsum_kernel<<<GRID_T, 256, 0, stream>>>(frag, frag + (size_t)HW * CDIM, label, parts);

    finalize_kernel<<<1, 256, 0, stream>>>(parts, out);
}